// Round 6
// baseline (304.070 us; speedup 1.0000x reference)
//
#include <hip/hip_runtime.h>
#include <hip/hip_bf16.h>
#include <math.h>

#define D_MODEL 1024
#define NHEAD   16
#define HEAD_DIM 64
#define BATCH   4
#define SEQ     2048

typedef __attribute__((ext_vector_type(8))) short bf16x8;
typedef __attribute__((ext_vector_type(4))) float f32x4;
typedef __attribute__((ext_vector_type(16))) float f32x16;

__device__ inline ushort f2bf(float f) {
  __hip_bfloat16 h = __float2bfloat16(f);
  return *reinterpret_cast<ushort*>(&h);
}
__device__ inline uint pk2(float a, float b) {
  return (uint)f2bf(a) | ((uint)f2bf(b) << 16);
}
__device__ inline float bf2f(ushort u) {
  return __uint_as_float((uint)u << 16);
}
__device__ inline f32x16 zero16() {
  f32x16 z;
#pragma unroll
  for (int i = 0; i < 16; ++i) z[i] = 0.f;
  return z;
}
// raw v_exp_f32 (2^x), no denormal-guard wrapper (logits are O(1))
__device__ inline float fexp2(float x) { return __builtin_amdgcn_exp2f(x); }

// async 16B global -> LDS (dest = wave-uniform base + lane*16; LDS must be unpadded)
__device__ inline void gld_lds16(const ushort* g, ushort* l) {
  __builtin_amdgcn_global_load_lds(
      (const __attribute__((address_space(1))) void*)g,
      (__attribute__((address_space(3))) void*)l, 16, 0, 0);
}

// ---------------- diagnostic fill ----------------
__global__ __launch_bounds__(256) void fill_f32(float* __restrict__ p, int n, float v) {
  int i = blockIdx.x * 256 + threadIdx.x;
  if (i < n) p[i] = v;
}

// ---------------- x: fp32 -> bf16 (8 elems/thread) ----------------
__global__ __launch_bounds__(256) void cast_bf16(const float* __restrict__ in,
                                                 ushort* __restrict__ out, int n8) {
  int i = blockIdx.x * 256 + threadIdx.x;
  if (i >= n8) return;
  const float4* p = (const float4*)(in + i * 8);
  float4 a = p[0], b = p[1];
  uint4 o;
  o.x = pk2(a.x, a.y); o.y = pk2(a.z, a.w);
  o.z = pk2(b.x, b.y); o.w = pk2(b.z, b.w);
  ((uint4*)out)[i] = o;
}

// ---------------- fp32 -> bf16 transpose: in[R][C] f32 -> out[C][R] bf16 ----------------
__global__ __launch_bounds__(256) void transpose_f32_bf16(const float* __restrict__ in,
                                                          ushort* __restrict__ out,
                                                          int R, int C) {
  __shared__ float tile[32][33];
  int tx = threadIdx.x, ty = threadIdx.y;   // block (32,8)
  int c0 = blockIdx.x * 32, r0 = blockIdx.y * 32;
#pragma unroll
  for (int k = 0; k < 4; ++k)
    tile[ty + 8 * k][tx] = in[(size_t)(r0 + ty + 8 * k) * C + c0 + tx];
  __syncthreads();
#pragma unroll
  for (int k = 0; k < 4; ++k)
    out[(size_t)(c0 + ty + 8 * k) * R + r0 + tx] = f2bf(tile[tx][ty + 8 * k]);
}

// ---------------- phase-pipelined MFMA GEMM: 256x128 tile, BK=64, 8 waves ----------------
// C[M][N] = A[M][K] * BT[N][K]^T, bf16 in, OutT out.
// T2 st_16x32 LDS swizzle (byte ^= ((byte>>9)&1)<<5), both-sides: linear gld_lds dest +
// inverse-swizzled GLOBAL source + swizzled ds_read (rule #21, m201 pattern).
// Raw s_barrier (no compiler vmcnt-drain); the only cross-wave edge (staged loads ->
// next tile's ds_reads) is fenced by an explicit vmcnt(0) memory-clobber asm at the
// tile boundary, ~2 phases (~1000 cyc) after issue -> cheap drain (T14 issue-early).
// 2 phases per K-tile (M-quadrants of the wave's 128x32 output): 12 ds_read_b128 +
// 16 MFMA per phase, setprio(1) around the MFMA cluster (T5).
__device__ inline bf16x8 lds_read_swz(const ushort* base, int byteoff) {
  byteoff ^= ((byteoff >> 9) & 1) << 5;
  return *(const bf16x8*)((const char*)base + byteoff);
}

template <typename OutT>
__global__ __launch_bounds__(512, 2) void gemm_mfma256(const ushort* __restrict__ A,
                                                       const ushort* __restrict__ BT,
                                                       OutT* __restrict__ C,
                                                       int M, int N, int K) {
  __shared__ ushort AS[2][256 * 64];   // 32 KB per buf
  __shared__ ushort BS[2][128 * 64];   // 16 KB per buf

  const int tid = threadIdx.x;
  const int w = tid >> 6, lane = tid & 63;
  const int quad = lane >> 4, l16 = lane & 15;
  const int wm = w >> 2, wn = w & 3;   // 2M x 4N waves; per-wave out 128x32

  // T1: XCD-aware bijective swizzle (grids here: 768, 256 -- both %8==0)
  int bx = blockIdx.x, by = blockIdx.y;
  {
    int nwg = gridDim.x * gridDim.y;
    if ((nwg & 7) == 0) {
      int bid = by * gridDim.x + bx;
      int chunk = nwg >> 3;
      bid = (bid & 7) * chunk + (bid >> 3);
      bx = bid % gridDim.x;
      by = bid / gridDim.x;
    }
  }
  const int m0 = by * 256, n0 = bx * 128;

  f32x4 acc[8][2];
#pragma unroll
  for (int mt = 0; mt < 8; ++mt)
#pragma unroll
    for (int nt = 0; nt < 2; ++nt) acc[mt][nt] = (f32x4){0.f, 0.f, 0.f, 0.f};

  // staging maps: A = 4 issues (32 KB), B = 2 issues (16 KB). For each linear LDS
  // byte x, load global element at inverse-swizzled position s(x) (s = involution).
  const ushort* asrc[4];
  const ushort* bsrc[2];
  uint adst[4], bdst[2];               // ushort offsets, wave-uniform
#pragma unroll
  for (int i = 0; i < 4; ++i) {
    int x = (i * 512 + tid) * 16;
    int sx = x ^ (((x >> 9) & 1) << 5);
    asrc[i] = A + (size_t)(m0 + (sx >> 7)) * K + ((sx & 127) >> 1);
    adst[i] = (uint)(i * 512 + w * 64) * 8;
  }
#pragma unroll
  for (int i = 0; i < 2; ++i) {
    int x = (i * 512 + tid) * 16;
    int sx = x ^ (((x >> 9) & 1) << 5);
    bsrc[i] = BT + (size_t)(n0 + (sx >> 7)) * K + ((sx & 127) >> 1);
    bdst[i] = (uint)(i * 512 + w * 64) * 8;
  }

  const int NKT = K >> 6;

  // prologue: stage tile 0 -> buf0
#pragma unroll
  for (int i = 0; i < 4; ++i) gld_lds16(asrc[i], AS[0] + adst[i]);
#pragma unroll
  for (int i = 0; i < 2; ++i) gld_lds16(bsrc[i], BS[0] + bdst[i]);
  asm volatile("s_waitcnt vmcnt(0)" ::: "memory");
  __builtin_amdgcn_s_barrier();

  for (int kt = 0; kt < NKT; ++kt) {
    const int cur = kt & 1;
    const int k0n = (kt + 1) << 6;

    // ---- phase A: issue next-tile staging EARLY (lands during ~2 phases of MFMA)
    if (kt + 1 < NKT) {
#pragma unroll
      for (int i = 0; i < 4; ++i) gld_lds16(asrc[i] + k0n, AS[cur ^ 1] + adst[i]);
#pragma unroll
      for (int i = 0; i < 2; ++i) gld_lds16(bsrc[i] + k0n, BS[cur ^ 1] + bdst[i]);
    }

    bf16x8 af[4][2], bf[2][2];
#pragma unroll
    for (int f = 0; f < 4; ++f)
#pragma unroll
      for (int kk = 0; kk < 2; ++kk)
        af[f][kk] = lds_read_swz(AS[cur], (wm * 128 + f * 16 + l16) * 128 + kk * 64 + quad * 16);
#pragma unroll
    for (int fn = 0; fn < 2; ++fn)
#pragma unroll
      for (int kk = 0; kk < 2; ++kk)
        bf[fn][kk] = lds_read_swz(BS[cur], (wn * 32 + fn * 16 + l16) * 128 + kk * 64 + quad * 16);
    __builtin_amdgcn_s_barrier();
    __builtin_amdgcn_s_setprio(1);
#pragma unroll
    for (int f = 0; f < 4; ++f)
#pragma unroll
      for (int fn = 0; fn < 2; ++fn)
#pragma unroll
        for (int kk = 0; kk < 2; ++kk)
          acc[f][fn] = __builtin_amdgcn_mfma_f32_16x16x32_bf16(af[f][kk], bf[fn][kk], acc[f][fn], 0, 0, 0);
    __builtin_amdgcn_s_setprio(0);
    __builtin_amdgcn_s_barrier();

    // ---- phase B: A-frags 4..7 (B-frags reused from registers)
#pragma unroll
    for (int f = 0; f < 4; ++f)
#pragma unroll
      for (int kk = 0; kk < 2; ++kk)
        af[f][kk] = lds_read_swz(AS[cur], (wm * 128 + 64 + f * 16 + l16) * 128 + kk * 64 + quad * 16);
    __builtin_amdgcn_s_barrier();
    __builtin_amdgcn_s_setprio(1);
#pragma unroll
    for (int f = 0; f < 4; ++f)
#pragma unroll
      for (int fn = 0; fn < 2; ++fn)
#pragma unroll
        for (int kk = 0; kk < 2; ++kk)
          acc[4 + f][fn] = __builtin_amdgcn_mfma_f32_16x16x32_bf16(af[f][kk], bf[fn][kk], acc[4 + f][fn], 0, 0, 0);
    __builtin_amdgcn_s_setprio(0);

    // ---- tile boundary: all staged loads landed before anyone reads buf[cur^1]
    asm volatile("s_waitcnt vmcnt(0)" ::: "memory");
    __builtin_amdgcn_s_barrier();
  }

  // ---- epilogue: C row = m0 + wm*128 + mt*16 + quad*4 + r ; col = n0 + wn*32 + nt*16 + l16
#pragma unroll
  for (int mt = 0; mt < 8; ++mt) {
#pragma unroll
    for (int nt = 0; nt < 2; ++nt) {
#pragma unroll
      for (int r = 0; r < 4; ++r) {
        size_t idx = (size_t)(m0 + wm * 128 + mt * 16 + quad * 4 + r) * N + n0 + wn * 32 + nt * 16 + l16;
        if constexpr (sizeof(OutT) == 4) C[idx] = acc[mt][nt][r];
        else                             C[idx] = f2bf(acc[mt][nt][r]);
      }
    }
  }
}

// ---------------- MFMA flash attention, 32x32x16 + in-register softmax ----------------
// (unchanged from R4 -- verified: absmax 1.95e-3, 93 us, conflicts 0)
#define KST 72
#define VST 72
#define NT  (SEQ / 64)
__global__ __launch_bounds__(256, 4) void attn_mfma(const ushort* __restrict__ qkv,
                                                    ushort* __restrict__ attn_o) {
  __shared__ ushort Ks[2][64 * KST];     // K[key][d]
  __shared__ ushort VTs[2][64 * VST];    // V^T[d][key]

  const int tid = threadIdx.x;
  const int w = tid >> 6, lane = tid & 63;
  const int q32 = lane & 31, hi = lane >> 5;

  // XCD-chunked swizzle (bijective): all 16 q-blocks of a head on one XCD.
  const int f = blockIdx.x;
  const int xcd = f & 7;
  const int j = f >> 3;                  // 0..127
  const int qb = j & 15;
  const int hb = ((j >> 4) << 3) | xcd;  // 0..63
  const int h = hb & 15, b = hb >> 4;
  const int q0 = qb * 128;

  const float qscale = 0.125f * 1.44269504088896f;
  bf16x8 qfrag[4];
  {
    const ushort* qrow = qkv + (size_t)(b * SEQ + q0 + w * 32 + q32) * 3072 + h * 64;
#pragma unroll
    for (int dd = 0; dd < 4; ++dd) {
      bf16x8 fq = *(const bf16x8*)(qrow + dd * 16 + hi * 8);
#pragma unroll
      for (int jj = 0; jj < 8; ++jj)
        fq[jj] = (short)f2bf(bf2f((ushort)fq[jj]) * qscale);
      qfrag[dd] = fq;
    }
  }

  f32x16 oacc0 = zero16(), oacc1 = zero16(), lacc = zero16();

  bf16x8 ones;
#pragma unroll
  for (int jj = 0; jj < 8; ++jj) ones[jj] = (short)0x3F80;  // bf16 1.0

  const int sr = tid >> 2, sc = tid & 3;   // K: row sr, 16-col group sc
  const int kp = tid & 31, dg = tid >> 5;  // V: key pair kp, 8-d group dg

  const size_t kstep = (size_t)64 * 3072;
  const ushort* kbase = qkv + (size_t)(b * SEQ + sr) * 3072 + 1024 + h * 64 + sc * 16;
  const ushort* vbase = qkv + (size_t)(b * SEQ + 2 * kp) * 3072 + 2048 + h * 64 + dg * 8;

  // prologue: load tile 0 -> regs -> buf0 (loop-top barrier covers the writes)
  uint4 kreg0, kreg1, vreg0, vreg1;
  {
    const uint4* ks = (const uint4*)kbase;
    kreg0 = ks[0]; kreg1 = ks[1];
    vreg0 = *(const uint4*)vbase;
    vreg1 = *(const uint4*)(vbase + 3072);
    uint4* kdst = (uint4*)(Ks[0] + sr * KST + sc * 16);
    kdst[0] = kreg0; kdst[1] = kreg1;
    const ushort* ae = (const ushort*)&vreg0;
    const ushort* ce = (const ushort*)&vreg1;
#pragma unroll
    for (int jj = 0; jj < 8; ++jj) {
      VTs[0][(dg * 8 + jj) * VST + 2 * kp]     = ae[jj];
      VTs[0][(dg * 8 + jj) * VST + 2 * kp + 1] = ce[jj];
    }
  }

  for (int kt = 0; kt < NT; ++kt) {
    const int cur = kt & 1;
    __syncthreads();   // writes of buf[cur] (prev iter / prologue) complete

    // ---- prefetch issue: tile kt+1 -> regs (lands during QK+softmax+PV)
    if (kt + 1 < NT) {
      const uint4* ks = (const uint4*)(kbase + (size_t)(kt + 1) * kstep);
      kreg0 = ks[0]; kreg1 = ks[1];
      vreg0 = *(const uint4*)(vbase + (size_t)(kt + 1) * kstep);
      vreg1 = *(const uint4*)(vbase + (size_t)(kt + 1) * kstep + 3072);
    }

    // ---- QK^T (swapped), both 32-key halves first (ILP: SM0 can overlap QK1)
    f32x16 sacc0 = zero16(), sacc1 = zero16();
    __builtin_amdgcn_s_setprio(1);
#pragma unroll
    for (int dd = 0; dd < 4; ++dd) {
      bf16x8 kf0 = *(const bf16x8*)(Ks[cur] + (q32)*KST + dd * 16 + hi * 8);
      bf16x8 kf1 = *(const bf16x8*)(Ks[cur] + (32 + q32) * KST + dd * 16 + hi * 8);
      sacc0 = __builtin_amdgcn_mfma_f32_32x32x16_bf16(kf0, qfrag[dd], sacc0, 0, 0, 0);
      sacc1 = __builtin_amdgcn_mfma_f32_32x32x16_bf16(kf1, qfrag[dd], sacc1, 0, 0, 0);
    }
    __builtin_amdgcn_s_setprio(0);

    // ---- in-register softmax -> pa[kb2] PV A-fragments
    bf16x8 pa[4];
#pragma unroll
    for (int kblk = 0; kblk < 2; ++kblk) {
      const f32x16& sacc = kblk ? sacc1 : sacc0;
      uint d0[4], d1[4];
#pragma unroll
      for (int p = 0; p < 4; ++p) {
        d0[p] = pk2(fexp2(sacc[4 * p + 0]), fexp2(sacc[4 * p + 1]));
        d1[p] = pk2(fexp2(sacc[4 * p + 2]), fexp2(sacc[4 * p + 3]));
      }
      // permlane32_swap(A=d[2k2], B=d[2k2+1]) -> fr = {A0,A1,B0,B1} (traced R2)
#pragma unroll
      for (int k2 = 0; k2 < 2; ++k2) {
        uint A0 = d0[2 * k2], B0 = d0[2 * k2 + 1];
        uint A1 = d1[2 * k2], B1 = d1[2 * k2 + 1];
        asm("v_permlane32_swap_b32 %0, %1" : "+v"(A0), "+v"(B0));
        asm("v_permlane32_swap_b32 %0, %1" : "+v"(A1), "+v"(B1));
        uint4 fr = {A0, A1, B0, B1};
        pa[kblk * 2 + k2] = *(bf16x8*)&fr;
        lacc = __builtin_amdgcn_mfma_f32_32x32x16_bf16(pa[kblk * 2 + k2], ones, lacc, 0, 0, 0);
      }
    }

    // ---- O += P V : A = pa[kb2] (in regs), B = V^T rows -> V[key][d] frags
    __builtin_amdgcn_s_setprio(1);
#pragma unroll
    for (int kb2 = 0; kb2 < 4; ++kb2) {
      bf16x8 vf0 = *(const bf16x8*)(VTs[cur] + (q32)*VST + kb2 * 16 + hi * 8);
      bf16x8 vf1 = *(const bf16x8*)(VTs[cur] + (32 + q32) * VST + kb2 * 16 + hi * 8);
      oacc0 = __builtin_amdgcn_mfma_f32_32x32x16_bf16(pa[kb2], vf0, oacc0, 0, 0, 0);
      oacc1 = __builtin_amdgcn_mfma_f32_32x32x16_bf16(pa[kb2], vf1, oacc1, 0, 0, 0);
    }
    __builtin_amdgcn_s_setprio(0);

    // ---- stage-write: regs (tile kt+1) -> buf[cur^1]; overlaps other waves' PV.
    if (kt + 1 < NT) {
      uint4* kdst = (uint4*)(Ks[cur ^ 1] + sr * KST + sc * 16);
      kdst[0] = kreg0; kdst[1] = kreg1;
      const ushort* ae = (const ushort*)&vreg0;
      const ushort* ce = (const ushort*)&vreg1;
#pragma unroll
      for (int jj = 0; jj < 8; ++jj) {
        VTs[cur ^ 1][(dg * 8 + jj) * VST + 2 * kp]     = ae[jj];
        VTs[cur ^ 1][(dg * 8 + jj) * VST + 2 * kp + 1] = ce[jj];
      }
    }
  }

  // ---- epilogue: row = (reg&3) + 8*(reg>>2) + 4*hi, col = q32 (same layout for L)
#pragma unroll
  for (int p = 0; p < 4; ++p) {
#pragma unroll
    for (int r = 0; r < 4; ++r) {
      int qrow = r + 8 * p + 4 * hi;
      float linv = 1.0f / lacc[4 * p + r];
      ushort* orow = attn_o + (size_t)(b * SEQ + q0 + w * 32 + qrow) * 1024 + h * 64 + q32;
      orow[0]  = f2bf(oacc0[4 * p + r] * linv);
      orow[32] = f2bf(oacc1[4 * p + r] * linv);
    }
  }
}

extern "C" void kernel_launch(void* const* d_in, const int* in_sizes, int n_in,
                              void* d_out, int out_size, void* d_ws, size_t ws_size,
                              hipStream_t stream) {
  bool ok_n  = (n_in == 3);
  bool ok_s0 = ok_n && (in_sizes[0] == 4 * 2048 * 1024);
  bool ok_s1 = ok_n && (in_sizes[1] == 1024 * 3072);
  bool ok_s2 = ok_n && (in_sizes[2] == 1024 * 1024);
  bool ok_o  = (out_size == 4 * 2048 * 1024);
  bool ok_w  = (ws_size >= (size_t)8192 * 3072 * 4);
  if (!(ok_n && ok_s0 && ok_s1 && ok_s2 && ok_o && ok_w)) {
    float c = 64.0f + 1.0f * ok_n + 2.0f * ok_s0 + 4.0f * ok_s1 +
              8.0f * ok_s2 + 16.0f * ok_o + 32.0f * ok_w;
    fill_f32<<<(out_size + 255) / 256, 256, 0, stream>>>((float*)d_out, out_size, c);
    return;
  }

  const float* x     = (const float*)d_in[0];  // [8192][1024]
  const float* w_qkv = (const float*)d_in[1];  // [1024][3072]
  const float* w_out = (const float*)d_in[2];  // [1024][1024]

  char* ws = (char*)d_ws;
  ushort* qkv    = (ushort*)ws;                                  // 48 MB
  ushort* xb     = (ushort*)(ws + (size_t)48 * 1024 * 1024);     // 16 MB
  ushort* attn_o = (ushort*)(ws + (size_t)64 * 1024 * 1024);     // 16 MB
  ushort* wqkvT  = (ushort*)(ws + (size_t)80 * 1024 * 1024);     // 6 MB
  ushort* woutT  = (ushort*)(ws + (size_t)86 * 1024 * 1024);     // 2 MB

  cast_bf16<<<dim3(8192 * 1024 / 8 / 256), dim3(256), 0, stream>>>(x, xb, 8192 * 1024 / 8);
  transpose_f32_bf16<<<dim3(3072 / 32, 1024 / 32), dim3(32, 8), 0, stream>>>(w_qkv, wqkvT, 1024, 3072);
  transpose_f32_bf16<<<dim3(1024 / 32, 1024 / 32), dim3(32, 8), 0, stream>>>(w_out, woutT, 1024, 1024);

  gemm_mfma256<ushort><<<dim3(3072 / 128, 8192 / 256), dim3(512), 0, stream>>>(
      xb, wqkvT, qkv, 8192, 3072, 1024);

  attn_mfma<<<dim3(1024), dim3(256), 0, stream>>>(qkv, attn_o);

  gemm_mfma256<float><<<dim3(1024 / 128, 8192 / 256), dim3(512), 0, stream>>>(
      attn_o, woutT, (float*)d_out, 8192, 1024, 1024);
}

// Round 7
// 286.314 us; speedup vs baseline: 1.0620x; 1.0620x over previous
//
#include <hip/hip_runtime.h>
#include <hip/hip_bf16.h>
#include <math.h>

#define D_MODEL 1024
#define NHEAD   16
#define HEAD_DIM 64
#define BATCH   4
#define SEQ     2048

typedef __attribute__((ext_vector_type(8))) short bf16x8;
typedef __attribute__((ext_vector_type(4))) float f32x4;
typedef __attribute__((ext_vector_type(16))) float f32x16;

__device__ inline ushort f2bf(float f) {
  __hip_bfloat16 h = __float2bfloat16(f);
  return *reinterpret_cast<ushort*>(&h);
}
__device__ inline uint pk2(float a, float b) {
  return (uint)f2bf(a) | ((uint)f2bf(b) << 16);
}
__device__ inline float bf2f(ushort u) {
  return __uint_as_float((uint)u << 16);
}
__device__ inline f32x16 zero16() {
  f32x16 z;
#pragma unroll
  for (int i = 0; i < 16; ++i) z[i] = 0.f;
  return z;
}
// raw v_exp_f32 (2^x), no denormal-guard wrapper (logits are O(1))
__device__ inline float fexp2(float x) { return __builtin_amdgcn_exp2f(x); }

// async 16B global -> LDS (dest = wave-uniform base + lane*16; LDS must be unpadded)
__device__ inline void gld_lds16(const ushort* g, ushort* l) {
  __builtin_amdgcn_global_load_lds(
      (const __attribute__((address_space(1))) void*)g,
      (__attribute__((address_space(3))) void*)l, 16, 0, 0);
}

// ---------------- diagnostic fill ----------------
__global__ __launch_bounds__(256) void fill_f32(float* __restrict__ p, int n, float v) {
  int i = blockIdx.x * 256 + threadIdx.x;
  if (i < n) p[i] = v;
}

// ---------------- x: fp32 -> bf16 (8 elems/thread) ----------------
__global__ __launch_bounds__(256) void cast_bf16(const float* __restrict__ in,
                                                 ushort* __restrict__ out, int n8) {
  int i = blockIdx.x * 256 + threadIdx.x;
  if (i >= n8) return;
  const float4* p = (const float4*)(in + i * 8);
  float4 a = p[0], b = p[1];
  uint4 o;
  o.x = pk2(a.x, a.y); o.y = pk2(a.z, a.w);
  o.z = pk2(b.x, b.y); o.w = pk2(b.z, b.w);
  ((uint4*)out)[i] = o;
}

// ---------------- fp32 -> bf16 transpose: in[R][C] f32 -> out[C][R] bf16 ----------------
__global__ __launch_bounds__(256) void transpose_f32_bf16(const float* __restrict__ in,
                                                          ushort* __restrict__ out,
                                                          int R, int C) {
  __shared__ float tile[32][33];
  int tx = threadIdx.x, ty = threadIdx.y;   // block (32,8)
  int c0 = blockIdx.x * 32, r0 = blockIdx.y * 32;
#pragma unroll
  for (int k = 0; k < 4; ++k)
    tile[ty + 8 * k][tx] = in[(size_t)(r0 + ty + 8 * k) * C + c0 + tx];
  __syncthreads();
#pragma unroll
  for (int k = 0; k < 4; ++k)
    out[(size_t)(c0 + ty + 8 * k) * R + r0 + tx] = f2bf(tile[tx][ty + 8 * k]);
}

// ---------------- phase-pipelined MFMA GEMM: 256x128 tile, BK=64, 8 waves ----------------
// C[M][N] = A[M][K] * BT[N][K]^T, bf16 in, OutT out.
// R6 swizzle fix: rows are 128B; a wave's 16 l16-lanes read 16 consecutive rows at a
// fixed 16B slot -> unswizzled 16-way conflict. XOR (row&7)<<4 spreads across 8 slots
// (2 lanes/slot = free). Involution within a row -> both-sides application (rule #21):
// linear gld_lds dest + inverse-swizzled GLOBAL source + swizzled ds_read.
// R6 sync fix (race-audited): ONE barrier + ONE per-wave vmcnt(0) per K-tile.
//   edge a: buf[cur] staged@t-1 -> read@t: own-vmcnt(0) BEFORE barrier (loads had the
//           entire t-1 compute region to land -> drain normally free), barrier = all waves.
//   edge b: buf[cur^1] read@t-1 -> overwritten@t: issue AFTER barrier.
// Staging issue sits right after the barrier so loads get ds_read+64-MFMA (~700+cyc) to land.
__device__ inline bf16x8 lds_read_swz(const ushort* base, int byteoff) {
  byteoff ^= ((byteoff >> 7) & 7) << 4;
  return *(const bf16x8*)((const char*)base + byteoff);
}

template <typename OutT>
__global__ __launch_bounds__(512, 2) void gemm_mfma256(const ushort* __restrict__ A,
                                                       const ushort* __restrict__ BT,
                                                       OutT* __restrict__ C,
                                                       int M, int N, int K) {
  __shared__ ushort AS[2][256 * 64];   // 32 KB per buf
  __shared__ ushort BS[2][128 * 64];   // 16 KB per buf

  const int tid = threadIdx.x;
  const int w = tid >> 6, lane = tid & 63;
  const int quad = lane >> 4, l16 = lane & 15;
  const int wm = w >> 2, wn = w & 3;   // 2M x 4N waves; per-wave out 128x32

  // T1: XCD-aware bijective swizzle (grids here: 768, 256 -- both %8==0)
  int bx = blockIdx.x, by = blockIdx.y;
  {
    int nwg = gridDim.x * gridDim.y;
    if ((nwg & 7) == 0) {
      int bid = by * gridDim.x + bx;
      int chunk = nwg >> 3;
      bid = (bid & 7) * chunk + (bid >> 3);
      bx = bid % gridDim.x;
      by = bid / gridDim.x;
    }
  }
  const int m0 = by * 256, n0 = bx * 128;

  f32x4 acc[8][2];
#pragma unroll
  for (int mt = 0; mt < 8; ++mt)
#pragma unroll
    for (int nt = 0; nt < 2; ++nt) acc[mt][nt] = (f32x4){0.f, 0.f, 0.f, 0.f};

  // staging maps: A = 4 issues (32 KB), B = 2 issues (16 KB). For linear LDS byte x,
  // load global element at inverse-swizzled position s(x) = x ^ ((x>>7 & 7)<<4).
  const ushort* asrc[4];
  const ushort* bsrc[2];
  uint adst[4], bdst[2];               // ushort offsets, wave-uniform
#pragma unroll
  for (int i = 0; i < 4; ++i) {
    int x = (i * 512 + tid) * 16;
    int sx = x ^ (((x >> 7) & 7) << 4);
    asrc[i] = A + (size_t)(m0 + (sx >> 7)) * K + ((sx & 127) >> 1);
    adst[i] = (uint)(i * 512 + w * 64) * 8;
  }
#pragma unroll
  for (int i = 0; i < 2; ++i) {
    int x = (i * 512 + tid) * 16;
    int sx = x ^ (((x >> 7) & 7) << 4);
    bsrc[i] = BT + (size_t)(n0 + (sx >> 7)) * K + ((sx & 127) >> 1);
    bdst[i] = (uint)(i * 512 + w * 64) * 8;
  }

  const int NKT = K >> 6;

  // prologue: issue stage of tile 0 -> buf0 (gated by loop-top vmcnt+barrier)
#pragma unroll
  for (int i = 0; i < 4; ++i) gld_lds16(asrc[i], AS[0] + adst[i]);
#pragma unroll
  for (int i = 0; i < 2; ++i) gld_lds16(bsrc[i], BS[0] + bdst[i]);

  for (int kt = 0; kt < NKT; ++kt) {
    const int cur = kt & 1;

    asm volatile("s_waitcnt vmcnt(0)" ::: "memory");  // own buf[cur] loads landed
    __builtin_amdgcn_s_barrier();                     // all waves landed + done with t-1

    // ---- issue next-tile staging (safe: everyone is past reading buf[cur^1])
    if (kt + 1 < NKT) {
      const int k0n = (kt + 1) << 6;
#pragma unroll
      for (int i = 0; i < 4; ++i) gld_lds16(asrc[i] + k0n, AS[cur ^ 1] + adst[i]);
#pragma unroll
      for (int i = 0; i < 2; ++i) gld_lds16(bsrc[i] + k0n, BS[cur ^ 1] + bdst[i]);
    }

    // ---- ds_reads + MFMA (no further barriers; compiler tracks lgkmcnt)
    bf16x8 bfr[2][2], af[4][2];
#pragma unroll
    for (int fn = 0; fn < 2; ++fn)
#pragma unroll
      for (int kk = 0; kk < 2; ++kk)
        bfr[fn][kk] = lds_read_swz(BS[cur], (wn * 32 + fn * 16 + l16) * 128 + kk * 64 + quad * 16);
#pragma unroll
    for (int f = 0; f < 4; ++f)
#pragma unroll
      for (int kk = 0; kk < 2; ++kk)
        af[f][kk] = lds_read_swz(AS[cur], (wm * 128 + f * 16 + l16) * 128 + kk * 64 + quad * 16);
    __builtin_amdgcn_s_setprio(1);
#pragma unroll
    for (int f = 0; f < 4; ++f)
#pragma unroll
      for (int fn = 0; fn < 2; ++fn)
#pragma unroll
        for (int kk = 0; kk < 2; ++kk)
          acc[f][fn] = __builtin_amdgcn_mfma_f32_16x16x32_bf16(af[f][kk], bfr[fn][kk], acc[f][fn], 0, 0, 0);
    __builtin_amdgcn_s_setprio(0);
#pragma unroll
    for (int f = 0; f < 4; ++f)
#pragma unroll
      for (int kk = 0; kk < 2; ++kk)
        af[f][kk] = lds_read_swz(AS[cur], (wm * 128 + 64 + f * 16 + l16) * 128 + kk * 64 + quad * 16);
    __builtin_amdgcn_s_setprio(1);
#pragma unroll
    for (int f = 0; f < 4; ++f)
#pragma unroll
      for (int fn = 0; fn < 2; ++fn)
#pragma unroll
        for (int kk = 0; kk < 2; ++kk)
          acc[4 + f][fn] = __builtin_amdgcn_mfma_f32_16x16x32_bf16(af[f][kk], bfr[fn][kk], acc[4 + f][fn], 0, 0, 0);
    __builtin_amdgcn_s_setprio(0);
  }

  // ---- epilogue: C row = m0 + wm*128 + mt*16 + quad*4 + r ; col = n0 + wn*32 + nt*16 + l16
#pragma unroll
  for (int mt = 0; mt < 8; ++mt) {
#pragma unroll
    for (int nt = 0; nt < 2; ++nt) {
#pragma unroll
      for (int r = 0; r < 4; ++r) {
        size_t idx = (size_t)(m0 + wm * 128 + mt * 16 + quad * 4 + r) * N + n0 + wn * 32 + nt * 16 + l16;
        if constexpr (sizeof(OutT) == 4) C[idx] = acc[mt][nt][r];
        else                             C[idx] = f2bf(acc[mt][nt][r]);
      }
    }
  }
}

// ---------------- MFMA flash attention, 32x32x16 + in-register softmax ----------------
// (unchanged from R4 -- verified: absmax 1.95e-3, 93 us, conflicts 0)
#define KST 72
#define VST 72
#define NT  (SEQ / 64)
__global__ __launch_bounds__(256, 4) void attn_mfma(const ushort* __restrict__ qkv,
                                                    ushort* __restrict__ attn_o) {
  __shared__ ushort Ks[2][64 * KST];     // K[key][d]
  __shared__ ushort VTs[2][64 * VST];    // V^T[d][key]

  const int tid = threadIdx.x;
  const int w = tid >> 6, lane = tid & 63;
  const int q32 = lane & 31, hi = lane >> 5;

  // XCD-chunked swizzle (bijective): all 16 q-blocks of a head on one XCD.
  const int f = blockIdx.x;
  const int xcd = f & 7;
  const int j = f >> 3;                  // 0..127
  const int qb = j & 15;
  const int hb = ((j >> 4) << 3) | xcd;  // 0..63
  const int h = hb & 15, b = hb >> 4;
  const int q0 = qb * 128;

  const float qscale = 0.125f * 1.44269504088896f;
  bf16x8 qfrag[4];
  {
    const ushort* qrow = qkv + (size_t)(b * SEQ + q0 + w * 32 + q32) * 3072 + h * 64;
#pragma unroll
    for (int dd = 0; dd < 4; ++dd) {
      bf16x8 fq = *(const bf16x8*)(qrow + dd * 16 + hi * 8);
#pragma unroll
      for (int jj = 0; jj < 8; ++jj)
        fq[jj] = (short)f2bf(bf2f((ushort)fq[jj]) * qscale);
      qfrag[dd] = fq;
    }
  }

  f32x16 oacc0 = zero16(), oacc1 = zero16(), lacc = zero16();

  bf16x8 ones;
#pragma unroll
  for (int jj = 0; jj < 8; ++jj) ones[jj] = (short)0x3F80;  // bf16 1.0

  const int sr = tid >> 2, sc = tid & 3;   // K: row sr, 16-col group sc
  const int kp = tid & 31, dg = tid >> 5;  // V: key pair kp, 8-d group dg

  const size_t kstep = (size_t)64 * 3072;
  const ushort* kbase = qkv + (size_t)(b * SEQ + sr) * 3072 + 1024 + h * 64 + sc * 16;
  const ushort* vbase = qkv + (size_t)(b * SEQ + 2 * kp) * 3072 + 2048 + h * 64 + dg * 8;

  // prologue: load tile 0 -> regs -> buf0 (loop-top barrier covers the writes)
  uint4 kreg0, kreg1, vreg0, vreg1;
  {
    const uint4* ks = (const uint4*)kbase;
    kreg0 = ks[0]; kreg1 = ks[1];
    vreg0 = *(const uint4*)vbase;
    vreg1 = *(const uint4*)(vbase + 3072);
    uint4* kdst = (uint4*)(Ks[0] + sr * KST + sc * 16);
    kdst[0] = kreg0; kdst[1] = kreg1;
    const ushort* ae = (const ushort*)&vreg0;
    const ushort* ce = (const ushort*)&vreg1;
#pragma unroll
    for (int jj = 0; jj < 8; ++jj) {
      VTs[0][(dg * 8 + jj) * VST + 2 * kp]     = ae[jj];
      VTs[0][(dg * 8 + jj) * VST + 2 * kp + 1] = ce[jj];
    }
  }

  for (int kt = 0; kt < NT; ++kt) {
    const int cur = kt & 1;
    __syncthreads();   // writes of buf[cur] (prev iter / prologue) complete

    // ---- prefetch issue: tile kt+1 -> regs (lands during QK+softmax+PV)
    if (kt + 1 < NT) {
      const uint4* ks = (const uint4*)(kbase + (size_t)(kt + 1) * kstep);
      kreg0 = ks[0]; kreg1 = ks[1];
      vreg0 = *(const uint4*)(vbase + (size_t)(kt + 1) * kstep);
      vreg1 = *(const uint4*)(vbase + (size_t)(kt + 1) * kstep + 3072);
    }

    // ---- QK^T (swapped), both 32-key halves first (ILP: SM0 can overlap QK1)
    f32x16 sacc0 = zero16(), sacc1 = zero16();
    __builtin_amdgcn_s_setprio(1);
#pragma unroll
    for (int dd = 0; dd < 4; ++dd) {
      bf16x8 kf0 = *(const bf16x8*)(Ks[cur] + (q32)*KST + dd * 16 + hi * 8);
      bf16x8 kf1 = *(const bf16x8*)(Ks[cur] + (32 + q32) * KST + dd * 16 + hi * 8);
      sacc0 = __builtin_amdgcn_mfma_f32_32x32x16_bf16(kf0, qfrag[dd], sacc0, 0, 0, 0);
      sacc1 = __builtin_amdgcn_mfma_f32_32x32x16_bf16(kf1, qfrag[dd], sacc1, 0, 0, 0);
    }
    __builtin_amdgcn_s_setprio(0);

    // ---- in-register softmax -> pa[kb2] PV A-fragments
    bf16x8 pa[4];
#pragma unroll
    for (int kblk = 0; kblk < 2; ++kblk) {
      const f32x16& sacc = kblk ? sacc1 : sacc0;
      uint d0[4], d1[4];
#pragma unroll
      for (int p = 0; p < 4; ++p) {
        d0[p] = pk2(fexp2(sacc[4 * p + 0]), fexp2(sacc[4 * p + 1]));
        d1[p] = pk2(fexp2(sacc[4 * p + 2]), fexp2(sacc[4 * p + 3]));
      }
      // permlane32_swap(A=d[2k2], B=d[2k2+1]) -> fr = {A0,A1,B0,B1} (traced R2)
#pragma unroll
      for (int k2 = 0; k2 < 2; ++k2) {
        uint A0 = d0[2 * k2], B0 = d0[2 * k2 + 1];
        uint A1 = d1[2 * k2], B1 = d1[2 * k2 + 1];
        asm("v_permlane32_swap_b32 %0, %1" : "+v"(A0), "+v"(B0));
        asm("v_permlane32_swap_b32 %0, %1" : "+v"(A1), "+v"(B1));
        uint4 fr = {A0, A1, B0, B1};
        pa[kblk * 2 + k2] = *(bf16x8*)&fr;
        lacc = __builtin_amdgcn_mfma_f32_32x32x16_bf16(pa[kblk * 2 + k2], ones, lacc, 0, 0, 0);
      }
    }

    // ---- O += P V : A = pa[kb2] (in regs), B = V^T rows -> V[key][d] frags
    __builtin_amdgcn_s_setprio(1);
#pragma unroll
    for (int kb2 = 0; kb2 < 4; ++kb2) {
      bf16x8 vf0 = *(const bf16x8*)(VTs[cur] + (q32)*VST + kb2 * 16 + hi * 8);
      bf16x8 vf1 = *(const bf16x8*)(VTs[cur] + (32 + q32) * VST + kb2 * 16 + hi * 8);
      oacc0 = __builtin_amdgcn_mfma_f32_32x32x16_bf16(pa[kb2], vf0, oacc0, 0, 0, 0);
      oacc1 = __builtin_amdgcn_mfma_f32_32x32x16_bf16(pa[kb2], vf1, oacc1, 0, 0, 0);
    }
    __builtin_amdgcn_s_setprio(0);

    // ---- stage-write: regs (tile kt+1) -> buf[cur^1]; overlaps other waves' PV.
    if (kt + 1 < NT) {
      uint4* kdst = (uint4*)(Ks[cur ^ 1] + sr * KST + sc * 16);
      kdst[0] = kreg0; kdst[1] = kreg1;
      const ushort* ae = (const ushort*)&vreg0;
      const ushort* ce = (const ushort*)&vreg1;
#pragma unroll
      for (int jj = 0; jj < 8; ++jj) {
        VTs[cur ^ 1][(dg * 8 + jj) * VST + 2 * kp]     = ae[jj];
        VTs[cur ^ 1][(dg * 8 + jj) * VST + 2 * kp + 1] = ce[jj];
      }
    }
  }

  // ---- epilogue: row = (reg&3) + 8*(reg>>2) + 4*hi, col = q32 (same layout for L)
#pragma unroll
  for (int p = 0; p < 4; ++p) {
#pragma unroll
    for (int r = 0; r < 4; ++r) {
      int qrow = r + 8 * p + 4 * hi;
      float linv = 1.0f / lacc[4 * p + r];
      ushort* orow = attn_o + (size_t)(b * SEQ + q0 + w * 32 + qrow) * 1024 + h * 64 + q32;
      orow[0]  = f2bf(oacc0[4 * p + r] * linv);
      orow[32] = f2bf(oacc1[4 * p + r] * linv);
    }
  }
}

extern "C" void kernel_launch(void* const* d_in, const int* in_sizes, int n_in,
                              void* d_out, int out_size, void* d_ws, size_t ws_size,
                              hipStream_t stream) {
  bool ok_n  = (n_in == 3);
  bool ok_s0 = ok_n && (in_sizes[0] == 4 * 2048 * 1024);
  bool ok_s1 = ok_n && (in_sizes[1] == 1024 * 3072);
  bool ok_s2 = ok_n && (in_sizes[2] == 1024 * 1024);
  bool ok_o  = (out_size == 4 * 2048 * 1024);
  bool ok_w  = (ws_size >= (size_t)8192 * 3072 * 4);
  if (!(ok_n && ok_s0 && ok_s1 && ok_s2 && ok_o && ok_w)) {
    float c = 64.0f + 1.0f * ok_n + 2.0f * ok_s0 + 4.0f * ok_s1 +
              8.0f * ok_s2 + 16.0f * ok_o + 32.0f * ok_w;
    fill_f32<<<(out_size + 255) / 256, 256, 0, stream>>>((float*)d_out, out_size, c);
    return;
  }

  const float* x     = (const float*)d_in[0];  // [8192][1024]
  const float* w_qkv = (const float*)d_in[1];  // [1024][3072]
  const float* w_out = (const float*)d_in[2];  // [1024][1024]

  char* ws = (char*)d_ws;
  ushort* qkv    = (ushort*)ws;                                  // 48 MB
  ushort* xb     = (ushort*)(ws + (size_t)48 * 1024 * 1024);     // 16 MB
  ushort* attn_o = (ushort*)(ws + (size_t)64 * 1024 * 1024);     // 16 MB
  ushort* wqkvT  = (ushort*)(ws + (size_t)80 * 1024 * 1024);     // 6 MB
  ushort* woutT  = (ushort*)(ws + (size_t)86 * 1024 * 1024);     // 2 MB

  cast_bf16<<<dim3(8192 * 1024 / 8 / 256), dim3(256), 0, stream>>>(x, xb, 8192 * 1024 / 8);
  transpose_f32_bf16<<<dim3(3072 / 32, 1024 / 32), dim3(32, 8), 0, stream>>>(w_qkv, wqkvT, 1024, 3072);
  transpose_f32_bf16<<<dim3(1024 / 32, 1024 / 32), dim3(32, 8), 0, stream>>>(w_out, woutT, 1024, 1024);

  gemm_mfma256<ushort><<<dim3(3072 / 128, 8192 / 256), dim3(512), 0, stream>>>(
      xb, wqkvT, qkv, 8192, 3072, 1024);

  attn_mfma<<<dim3(1024), dim3(256), 0, stream>>>(qkv, attn_o);

  gemm_mfma256<float><<<dim3(1024 / 128, 8192 / 256), dim3(512), 0, stream>>>(
      attn_o, woutT, (float*)d_out, 8192, 1024, 1024);
}

// Round 8
// 271.393 us; speedup vs baseline: 1.1204x; 1.0550x over previous
//
#include <hip/hip_runtime.h>
#include <hip/hip_bf16.h>
#include <math.h>

#define D_MODEL 1024
#define NHEAD   16
#define HEAD_DIM 64
#define BATCH   4
#define SEQ     2048

typedef __attribute__((ext_vector_type(8))) short bf16x8;
typedef __attribute__((ext_vector_type(4))) float f32x4;
typedef __attribute__((ext_vector_type(16))) float f32x16;

__device__ inline ushort f2bf(float f) {
  __hip_bfloat16 h = __float2bfloat16(f);
  return *reinterpret_cast<ushort*>(&h);
}
__device__ inline uint pk2(float a, float b) {
  return (uint)f2bf(a) | ((uint)f2bf(b) << 16);
}
__device__ inline float bf2f(ushort u) {
  return __uint_as_float((uint)u << 16);
}
__device__ inline f32x16 zero16() {
  f32x16 z;
#pragma unroll
  for (int i = 0; i < 16; ++i) z[i] = 0.f;
  return z;
}
// raw v_exp_f32 (2^x), no denormal-guard wrapper (logits are O(1))
__device__ inline float fexp2(float x) { return __builtin_amdgcn_exp2f(x); }

// async 16B global -> LDS (dest = wave-uniform base + lane*16; LDS must be unpadded)
__device__ inline void gld_lds16(const ushort* g, ushort* l) {
  __builtin_amdgcn_global_load_lds(
      (const __attribute__((address_space(1))) void*)g,
      (__attribute__((address_space(3))) void*)l, 16, 0, 0);
}

// ---------------- diagnostic fill ----------------
__global__ __launch_bounds__(256) void fill_f32(float* __restrict__ p, int n, float v) {
  int i = blockIdx.x * 256 + threadIdx.x;
  if (i < n) p[i] = v;
}

// ---------------- x: fp32 -> bf16 (8 elems/thread) ----------------
__global__ __launch_bounds__(256) void cast_bf16(const float* __restrict__ in,
                                                 ushort* __restrict__ out, int n8) {
  int i = blockIdx.x * 256 + threadIdx.x;
  if (i >= n8) return;
  const float4* p = (const float4*)(in + i * 8);
  float4 a = p[0], b = p[1];
  uint4 o;
  o.x = pk2(a.x, a.y); o.y = pk2(a.z, a.w);
  o.z = pk2(b.x, b.y); o.w = pk2(b.z, b.w);
  ((uint4*)out)[i] = o;
}

// ---------------- fp32 -> bf16 transpose: in[R][C] f32 -> out[C][R] bf16 ----------------
__global__ __launch_bounds__(256) void transpose_f32_bf16(const float* __restrict__ in,
                                                          ushort* __restrict__ out,
                                                          int R, int C) {
  __shared__ float tile[32][33];
  int tx = threadIdx.x, ty = threadIdx.y;   // block (32,8)
  int c0 = blockIdx.x * 32, r0 = blockIdx.y * 32;
#pragma unroll
  for (int k = 0; k < 4; ++k)
    tile[ty + 8 * k][tx] = in[(size_t)(r0 + ty + 8 * k) * C + c0 + tx];
  __syncthreads();
#pragma unroll
  for (int k = 0; k < 4; ++k)
    out[(size_t)(c0 + ty + 8 * k) * R + r0 + tx] = f2bf(tile[tx][ty + 8 * k]);
}

// ---------------- square-wave-tile MFMA GEMM template ----------------
// C[M][N] = A[M][K] * BT[N][K]^T, bf16 in, OutT out. BK=64.
// R7: 64x64 per-wave output tiles. LDS-read traffic per K-tile per CU =
// sum_waves (WR+WC)*BK*2B -- square wave tiles minimize it (R6's 128x32 was
// 160KB/K-tile -> MfmaUtil 21%; 64x64 gives 128KB + full occupancy).
// Schedule (R6, verified): single s_barrier + per-wave vmcnt(0) per K-tile;
// staging issue right after barrier gets the whole compute region to land.
// Swizzle (R6, verified): byte ^= ((byte>>7)&7)<<4 involution, applied on
// global source (inverse) + ds_read (forward); gld_lds dest stays linear.
__device__ inline bf16x8 lds_read_swz(const ushort* base, int byteoff) {
  byteoff ^= ((byteoff >> 7) & 7) << 4;
  return *(const bf16x8*)((const char*)base + byteoff);
}

template <int BM, int BN, int WM, int WN, typename OutT>
__global__ __launch_bounds__(WM * WN * 64, 2) void gemm_sq(const ushort* __restrict__ A,
                                                           const ushort* __restrict__ BT,
                                                           OutT* __restrict__ C,
                                                           int M, int N, int K) {
  constexpr int THREADS = WM * WN * 64;
  constexpr int WR = BM / WM;           // per-wave rows   (64)
  constexpr int WC = BN / WN;           // per-wave cols   (64)
  constexpr int MT = WR / 16;           // 4
  constexpr int NTC = WC / 16;          // 4
  constexpr int MH = MT / 2;            // phase split
  constexpr int NA = BM * 8 / THREADS;  // staging issues for A
  constexpr int NB = BN * 8 / THREADS;

  __shared__ ushort AS[2][BM * 64];
  __shared__ ushort BS[2][BN * 64];

  const int tid = threadIdx.x;
  const int w = tid >> 6, lane = tid & 63;
  const int quad = lane >> 4, l16 = lane & 15;
  const int wm = w / WN, wn = w % WN;

  // T1: XCD-aware bijective swizzle (grids here: 768, 512 -- both %8==0)
  int bx = blockIdx.x, by = blockIdx.y;
  {
    int nwg = gridDim.x * gridDim.y;
    if ((nwg & 7) == 0) {
      int bid = by * gridDim.x + bx;
      int chunk = nwg >> 3;
      bid = (bid & 7) * chunk + (bid >> 3);
      bx = bid % gridDim.x;
      by = bid / gridDim.x;
    }
  }
  const int m0 = by * BM, n0 = bx * BN;

  f32x4 acc[MT][NTC];
#pragma unroll
  for (int mt = 0; mt < MT; ++mt)
#pragma unroll
    for (int nt = 0; nt < NTC; ++nt) acc[mt][nt] = (f32x4){0.f, 0.f, 0.f, 0.f};

  // staging maps: for linear LDS byte x, global source at inverse-swizzled s(x)
  const ushort* asrc[NA];
  const ushort* bsrc[NB];
  uint adst[NA], bdst[NB];
#pragma unroll
  for (int i = 0; i < NA; ++i) {
    int x = (i * THREADS + tid) * 16;
    int sx = x ^ (((x >> 7) & 7) << 4);
    asrc[i] = A + (size_t)(m0 + (sx >> 7)) * K + ((sx & 127) >> 1);
    adst[i] = (uint)(i * THREADS + w * 64) * 8;
  }
#pragma unroll
  for (int i = 0; i < NB; ++i) {
    int x = (i * THREADS + tid) * 16;
    int sx = x ^ (((x >> 7) & 7) << 4);
    bsrc[i] = BT + (size_t)(n0 + (sx >> 7)) * K + ((sx & 127) >> 1);
    bdst[i] = (uint)(i * THREADS + w * 64) * 8;
  }

  const int NKT = K >> 6;

  // prologue: issue stage of tile 0 -> buf0 (gated by loop-top vmcnt+barrier)
#pragma unroll
  for (int i = 0; i < NA; ++i) gld_lds16(asrc[i], AS[0] + adst[i]);
#pragma unroll
  for (int i = 0; i < NB; ++i) gld_lds16(bsrc[i], BS[0] + bdst[i]);

  for (int kt = 0; kt < NKT; ++kt) {
    const int cur = kt & 1;

    asm volatile("s_waitcnt vmcnt(0)" ::: "memory");  // own buf[cur] loads landed
    __builtin_amdgcn_s_barrier();                     // all waves landed + done with t-1

    // ---- issue next-tile staging (safe: everyone is past reading buf[cur^1])
    if (kt + 1 < NKT) {
      const int k0n = (kt + 1) << 6;
#pragma unroll
      for (int i = 0; i < NA; ++i) gld_lds16(asrc[i] + k0n, AS[cur ^ 1] + adst[i]);
#pragma unroll
      for (int i = 0; i < NB; ++i) gld_lds16(bsrc[i] + k0n, BS[cur ^ 1] + bdst[i]);
    }

    // ---- B fragments once per K-tile (reused by both phases)
    bf16x8 bfr[NTC][2];
#pragma unroll
    for (int nt = 0; nt < NTC; ++nt)
#pragma unroll
      for (int kk = 0; kk < 2; ++kk)
        bfr[nt][kk] = lds_read_swz(BS[cur], (wn * WC + nt * 16 + l16) * 128 + kk * 64 + quad * 16);

    // ---- two phases of A-rows
#pragma unroll
    for (int ph = 0; ph < 2; ++ph) {
      bf16x8 af[MH][2];
#pragma unroll
      for (int f = 0; f < MH; ++f)
#pragma unroll
        for (int kk = 0; kk < 2; ++kk)
          af[f][kk] = lds_read_swz(AS[cur],
              (wm * WR + (ph * MH + f) * 16 + l16) * 128 + kk * 64 + quad * 16);
      __builtin_amdgcn_s_setprio(1);
#pragma unroll
      for (int f = 0; f < MH; ++f)
#pragma unroll
        for (int nt = 0; nt < NTC; ++nt)
#pragma unroll
          for (int kk = 0; kk < 2; ++kk)
            acc[ph * MH + f][nt] = __builtin_amdgcn_mfma_f32_16x16x32_bf16(
                af[f][kk], bfr[nt][kk], acc[ph * MH + f][nt], 0, 0, 0);
      __builtin_amdgcn_s_setprio(0);
    }
  }

  // ---- epilogue
#pragma unroll
  for (int mt = 0; mt < MT; ++mt) {
#pragma unroll
    for (int nt = 0; nt < NTC; ++nt) {
#pragma unroll
      for (int r = 0; r < 4; ++r) {
        size_t idx = (size_t)(m0 + wm * WR + mt * 16 + quad * 4 + r) * N
                     + n0 + wn * WC + nt * 16 + l16;
        if constexpr (sizeof(OutT) == 4) C[idx] = acc[mt][nt][r];
        else                             C[idx] = f2bf(acc[mt][nt][r]);
      }
    }
  }
}

// ---------------- MFMA flash attention, 32x32x16 + in-register softmax ----------------
// (unchanged from R4 -- verified: absmax 1.95e-3, ~95 us, conflicts 0)
#define KST 72
#define VST 72
#define NT  (SEQ / 64)
__global__ __launch_bounds__(256, 4) void attn_mfma(const ushort* __restrict__ qkv,
                                                    ushort* __restrict__ attn_o) {
  __shared__ ushort Ks[2][64 * KST];     // K[key][d]
  __shared__ ushort VTs[2][64 * VST];    // V^T[d][key]

  const int tid = threadIdx.x;
  const int w = tid >> 6, lane = tid & 63;
  const int q32 = lane & 31, hi = lane >> 5;

  // XCD-chunked swizzle (bijective): all 16 q-blocks of a head on one XCD.
  const int f = blockIdx.x;
  const int xcd = f & 7;
  const int j = f >> 3;                  // 0..127
  const int qb = j & 15;
  const int hb = ((j >> 4) << 3) | xcd;  // 0..63
  const int h = hb & 15, b = hb >> 4;
  const int q0 = qb * 128;

  const float qscale = 0.125f * 1.44269504088896f;
  bf16x8 qfrag[4];
  {
    const ushort* qrow = qkv + (size_t)(b * SEQ + q0 + w * 32 + q32) * 3072 + h * 64;
#pragma unroll
    for (int dd = 0; dd < 4; ++dd) {
      bf16x8 fq = *(const bf16x8*)(qrow + dd * 16 + hi * 8);
#pragma unroll
      for (int jj = 0; jj < 8; ++jj)
        fq[jj] = (short)f2bf(bf2f((ushort)fq[jj]) * qscale);
      qfrag[dd] = fq;
    }
  }

  f32x16 oacc0 = zero16(), oacc1 = zero16(), lacc = zero16();

  bf16x8 ones;
#pragma unroll
  for (int jj = 0; jj < 8; ++jj) ones[jj] = (short)0x3F80;  // bf16 1.0

  const int sr = tid >> 2, sc = tid & 3;   // K: row sr, 16-col group sc
  const int kp = tid & 31, dg = tid >> 5;  // V: key pair kp, 8-d group dg

  const size_t kstep = (size_t)64 * 3072;
  const ushort* kbase = qkv + (size_t)(b * SEQ + sr) * 3072 + 1024 + h * 64 + sc * 16;
  const ushort* vbase = qkv + (size_t)(b * SEQ + 2 * kp) * 3072 + 2048 + h * 64 + dg * 8;

  // prologue: load tile 0 -> regs -> buf0 (loop-top barrier covers the writes)
  uint4 kreg0, kreg1, vreg0, vreg1;
  {
    const uint4* ks = (const uint4*)kbase;
    kreg0 = ks[0]; kreg1 = ks[1];
    vreg0 = *(const uint4*)vbase;
    vreg1 = *(const uint4*)(vbase + 3072);
    uint4* kdst = (uint4*)(Ks[0] + sr * KST + sc * 16);
    kdst[0] = kreg0; kdst[1] = kreg1;
    const ushort* ae = (const ushort*)&vreg0;
    const ushort* ce = (const ushort*)&vreg1;
#pragma unroll
    for (int jj = 0; jj < 8; ++jj) {
      VTs[0][(dg * 8 + jj) * VST + 2 * kp]     = ae[jj];
      VTs[0][(dg * 8 + jj) * VST + 2 * kp + 1] = ce[jj];
    }
  }

  for (int kt = 0; kt < NT; ++kt) {
    const int cur = kt & 1;
    __syncthreads();   // writes of buf[cur] (prev iter / prologue) complete

    // ---- prefetch issue: tile kt+1 -> regs (lands during QK+softmax+PV)
    if (kt + 1 < NT) {
      const uint4* ks = (const uint4*)(kbase + (size_t)(kt + 1) * kstep);
      kreg0 = ks[0]; kreg1 = ks[1];
      vreg0 = *(const uint4*)(vbase + (size_t)(kt + 1) * kstep);
      vreg1 = *(const uint4*)(vbase + (size_t)(kt + 1) * kstep + 3072);
    }

    // ---- QK^T (swapped), both 32-key halves first (ILP: SM0 can overlap QK1)
    f32x16 sacc0 = zero16(), sacc1 = zero16();
    __builtin_amdgcn_s_setprio(1);
#pragma unroll
    for (int dd = 0; dd < 4; ++dd) {
      bf16x8 kf0 = *(const bf16x8*)(Ks[cur] + (q32)*KST + dd * 16 + hi * 8);
      bf16x8 kf1 = *(const bf16x8*)(Ks[cur] + (32 + q32) * KST + dd * 16 + hi * 8);
      sacc0 = __builtin_amdgcn_mfma_f32_32x32x16_bf16(kf0, qfrag[dd], sacc0, 0, 0, 0);
      sacc1 = __builtin_amdgcn_mfma_f32_32x32x16_bf16(kf1, qfrag[dd], sacc1, 0, 0, 0);
    }
    __builtin_amdgcn_s_setprio(0);

    // ---- in-register softmax -> pa[kb2] PV A-fragments
    bf16x8 pa[4];
#pragma unroll
    for (int kblk = 0; kblk < 2; ++kblk) {
      const f32x16& sacc = kblk ? sacc1 : sacc0;
      uint d0[4], d1[4];
#pragma unroll
      for (int p = 0; p < 4; ++p) {
        d0[p] = pk2(fexp2(sacc[4 * p + 0]), fexp2(sacc[4 * p + 1]));
        d1[p] = pk2(fexp2(sacc[4 * p + 2]), fexp2(sacc[4 * p + 3]));
      }
      // permlane32_swap(A=d[2k2], B=d[2k2+1]) -> fr = {A0,A1,B0,B1} (traced R2)
#pragma unroll
      for (int k2 = 0; k2 < 2; ++k2) {
        uint A0 = d0[2 * k2], B0 = d0[2 * k2 + 1];
        uint A1 = d1[2 * k2], B1 = d1[2 * k2 + 1];
        asm("v_permlane32_swap_b32 %0, %1" : "+v"(A0), "+v"(B0));
        asm("v_permlane32_swap_b32 %0, %1" : "+v"(A1), "+v"(B1));
        uint4 fr = {A0, A1, B0, B1};
        pa[kblk * 2 + k2] = *(bf16x8*)&fr;
        lacc = __builtin_amdgcn_mfma_f32_32x32x16_bf16(pa[kblk * 2 + k2], ones, lacc, 0, 0, 0);
      }
    }

    // ---- O += P V : A = pa[kb2] (in regs), B = V^T rows -> V[key][d] frags
    __builtin_amdgcn_s_setprio(1);
#pragma unroll
    for (int kb2 = 0; kb2 < 4; ++kb2) {
      bf16x8 vf0 = *(const bf16x8*)(VTs[cur] + (q32)*VST + kb2 * 16 + hi * 8);
      bf16x8 vf1 = *(const bf16x8*)(VTs[cur] + (32 + q32) * VST + kb2 * 16 + hi * 8);
      oacc0 = __builtin_amdgcn_mfma_f32_32x32x16_bf16(pa[kb2], vf0, oacc0, 0, 0, 0);
      oacc1 = __builtin_amdgcn_mfma_f32_32x32x16_bf16(pa[kb2], vf1, oacc1, 0, 0, 0);
    }
    __builtin_amdgcn_s_setprio(0);

    // ---- stage-write: regs (tile kt+1) -> buf[cur^1]; overlaps other waves' PV.
    if (kt + 1 < NT) {
      uint4* kdst = (uint4*)(Ks[cur ^ 1] + sr * KST + sc * 16);
      kdst[0] = kreg0; kdst[1] = kreg1;
      const ushort* ae = (const ushort*)&vreg0;
      const ushort* ce = (const ushort*)&vreg1;
#pragma unroll
      for (int jj = 0; jj < 8; ++jj) {
        VTs[cur ^ 1][(dg * 8 + jj) * VST + 2 * kp]     = ae[jj];
        VTs[cur ^ 1][(dg * 8 + jj) * VST + 2 * kp + 1] = ce[jj];
      }
    }
  }

  // ---- epilogue: row = (reg&3) + 8*(reg>>2) + 4*hi, col = q32 (same layout for L)
#pragma unroll
  for (int p = 0; p < 4; ++p) {
#pragma unroll
    for (int r = 0; r < 4; ++r) {
      int qrow = r + 8 * p + 4 * hi;
      float linv = 1.0f / lacc[4 * p + r];
      ushort* orow = attn_o + (size_t)(b * SEQ + q0 + w * 32 + qrow) * 1024 + h * 64 + q32;
      orow[0]  = f2bf(oacc0[4 * p + r] * linv);
      orow[32] = f2bf(oacc1[4 * p + r] * linv);
    }
  }
}

extern "C" void kernel_launch(void* const* d_in, const int* in_sizes, int n_in,
                              void* d_out, int out_size, void* d_ws, size_t ws_size,
                              hipStream_t stream) {
  bool ok_n  = (n_in == 3);
  bool ok_s0 = ok_n && (in_sizes[0] == 4 * 2048 * 1024);
  bool ok_s1 = ok_n && (in_sizes[1] == 1024 * 3072);
  bool ok_s2 = ok_n && (in_sizes[2] == 1024 * 1024);
  bool ok_o  = (out_size == 4 * 2048 * 1024);
  bool ok_w  = (ws_size >= (size_t)8192 * 3072 * 4);
  if (!(ok_n && ok_s0 && ok_s1 && ok_s2 && ok_o && ok_w)) {
    float c = 64.0f + 1.0f * ok_n + 2.0f * ok_s0 + 4.0f * ok_s1 +
              8.0f * ok_s2 + 16.0f * ok_o + 32.0f * ok_w;
    fill_f32<<<(out_size + 255) / 256, 256, 0, stream>>>((float*)d_out, out_size, c);
    return;
  }

  const float* x     = (const float*)d_in[0];  // [8192][1024]
  const float* w_qkv = (const float*)d_in[1];  // [1024][3072]
  const float* w_out = (const float*)d_in[2];  // [1024][1024]

  char* ws = (char*)d_ws;
  ushort* qkv    = (ushort*)ws;                                  // 48 MB
  ushort* xb     = (ushort*)(ws + (size_t)48 * 1024 * 1024);     // 16 MB
  ushort* attn_o = (ushort*)(ws + (size_t)64 * 1024 * 1024);     // 16 MB
  ushort* wqkvT  = (ushort*)(ws + (size_t)80 * 1024 * 1024);     // 6 MB
  ushort* woutT  = (ushort*)(ws + (size_t)86 * 1024 * 1024);     // 2 MB

  cast_bf16<<<dim3(8192 * 1024 / 8 / 256), dim3(256), 0, stream>>>(x, xb, 8192 * 1024 / 8);
  transpose_f32_bf16<<<dim3(3072 / 32, 1024 / 32), dim3(32, 8), 0, stream>>>(w_qkv, wqkvT, 1024, 3072);
  transpose_f32_bf16<<<dim3(1024 / 32, 1024 / 32), dim3(32, 8), 0, stream>>>(w_out, woutT, 1024, 1024);

  // gemm1: 128x256 tile, 8 waves of 64x64 -> grid 12x64 = 768 (3 full CU rounds)
  gemm_sq<128, 256, 2, 4, ushort><<<dim3(3072 / 256, 8192 / 128), dim3(512), 0, stream>>>(
      xb, wqkvT, qkv, 8192, 3072, 1024);

  attn_mfma<<<dim3(1024), dim3(256), 0, stream>>>(qkv, attn_o);

  // gemm2: 128x128 tile, 4 waves of 64x64 -> grid 8x64 = 512 (2 blocks/CU)
  gemm_sq<128, 128, 2, 2, float><<<dim3(1024 / 128, 8192 / 128), dim3(256), 0, stream>>>(
      attn_o, woutT, (float*)d_out, 8192, 1024, 1024);
}